// Round 1
// 477.091 us; speedup vs baseline: 1.0874x; 1.0874x over previous
//
#include <hip/hip_runtime.h>

// SelfAttention B=8 S=2048 D=1024 fp32 -> fp32, bf16 MFMA internally.
// R5: (a) f2b now uses native (__bf16) cast -> compiler emits
//     v_cvt_pk_bf16_f32 (RNE, same numerics) instead of ~5-op bit-trick per
//     element; cuts proj A-staging VALU cost ~5x.
//     (b) proj_gemm software-pipelines the fp32 A load: prefetch next K-tile
//     into registers before the pre-MFMA barrier, so A-load latency drains
//     under the same vmcnt(0) the B global_load_lds already pays.
// Pipeline:
//   build_idx; castW x3;
//   proj Q (fused cast) -> Qp; proj K (fused gather+cast) -> Kc;
//   proj V (fused gather+cast, transposed out) -> Vtc;
//   scores GEMM: p=(gn<cnt)?exp(s/32):0 -> bf16 probs + atomic rowsum
//   PV GEMM (K limited to cntp[b]), epilogue /rowsum -> fp32 out.
// GEMM core = m97-style: 128x128 tile, BK=32, 4 waves, 16x16x32 bf16 MFMA,
// 2-barrier K-loop; B staging async global_load_lds width=16.
// Workspace (~167MB): Qp[0,32M) Kc[32,64M) Vtc[64,96M) probs[96,160M)
//   weights[160,166M) rowsum/idx/cnt/cntp after.

#define BATCH 8
#define SEQ   2048
#define DM    1024

typedef __bf16 bf16x8 __attribute__((ext_vector_type(8)));
typedef float  f32x4  __attribute__((ext_vector_type(4)));
typedef unsigned short ushort8 __attribute__((ext_vector_type(8)));
typedef unsigned short ushort4v __attribute__((ext_vector_type(4)));

__device__ __forceinline__ unsigned short f2b(float f) {
    // Native cast: compiler emits v_cvt_pk_bf16_f32 pairs (RNE).
    __bf16 h = (__bf16)f;
    return __builtin_bit_cast(unsigned short, h);
}

__device__ __forceinline__ void stage_async(const unsigned short* g,
                                            unsigned short* l) {
    __builtin_amdgcn_global_load_lds(
        (const __attribute__((address_space(1))) void*)g,
        (__attribute__((address_space(3))) void*)l, 16, 0, 0);
}

// fragment load + 4x4 MFMA for one BK=32 staged tile
__device__ __forceinline__ void frag_mfma(const unsigned short* As,
                                          const unsigned short* Bs,
                                          f32x4 acc[4][4], int waveM, int waveN,
                                          int quad, int l16) {
    bf16x8 af[4], bf[4];
#pragma unroll
    for (int i = 0; i < 4; ++i)
        af[i] = *(const bf16x8*)(As + (waveM * 64 + i * 16 + l16) * 32 + quad * 8);
#pragma unroll
    for (int j = 0; j < 4; ++j)
        bf[j] = *(const bf16x8*)(Bs + (waveN * 64 + j * 16 + l16) * 32 + quad * 8);
#pragma unroll
    for (int i = 0; i < 4; ++i)
#pragma unroll
        for (int j = 0; j < 4; ++j)
            acc[i][j] = __builtin_amdgcn_mfma_f32_16x16x32_bf16(
                af[i], bf[j], acc[i][j], 0, 0, 0);
}

// ---------------- per-batch mask compaction index ----------------
__global__ __launch_bounds__(256) void build_idx(
    const int* __restrict__ mask, int* __restrict__ idx,
    int* __restrict__ cnt, int* __restrict__ cntp) {
    const int b = blockIdx.x;
    const int* m = mask + b * SEQ;
    const int t = threadIdx.x;
    __shared__ int sums[256];
    int loc[8], s = 0;
#pragma unroll
    for (int u = 0; u < 8; ++u) { loc[u] = (m[t * 8 + u] != 0); s += loc[u]; }
    sums[t] = s;
    __syncthreads();
    for (int off = 1; off < 256; off <<= 1) {
        int v = (t >= off) ? sums[t - off] : 0;
        __syncthreads();
        sums[t] += v;
        __syncthreads();
    }
    int base = sums[t] - s;   // exclusive prefix
#pragma unroll
    for (int u = 0; u < 8; ++u)
        if (loc[u]) idx[b * SEQ + base++] = t * 8 + u;
    if (t == 255) {
        cnt[b] = sums[255];
        cntp[b] = (sums[255] + 127) & ~127;
    }
}

// ---------------- cast fp32 -> bf16 (weights only) ----------------
__global__ void cast_bf16(const float* __restrict__ src,
                          unsigned short* __restrict__ dst, int n8) {
    int i = blockIdx.x * blockDim.x + threadIdx.x;
    if (i >= n8) return;
    const f32x4* s4 = (const f32x4*)src;
    f32x4 a = s4[2 * i], b = s4[2 * i + 1];
    ushort8 o;
    o[0] = f2b(a[0]); o[1] = f2b(a[1]); o[2] = f2b(a[2]); o[3] = f2b(a[3]);
    o[4] = f2b(b[0]); o[5] = f2b(b[1]); o[6] = f2b(b[2]); o[7] = f2b(b[3]);
    ((ushort8*)dst)[i] = o;
}

// ------------- projection GEMM with fused cast(+gather) A-staging -------------
// C[M,N] = cast(X)[M,K] * W[N,K]^T + bias.  X fp32 (gathered rows if GATHER),
// W bf16 async-staged.  TROUT: write C^T -> C[b][n][m] (V path).
// A fp32 loads are software-pipelined one K-step ahead (regs), so their
// latency drains under the same pre-barrier vmcnt(0) as the B stage.
// grid (8,16,8); swizzle batch = linear&7.
template <bool GATHER, bool TROUT>
__global__ __launch_bounds__(256) void proj_gemm(
    const float* __restrict__ X, const unsigned short* __restrict__ W,
    unsigned short* __restrict__ C, const float* __restrict__ bias,
    const int* __restrict__ idx, const int* __restrict__ cnt,
    const int* __restrict__ cntp) {
    const int l = blockIdx.x + 8 * (blockIdx.y + 16 * blockIdx.z);
    const int bz = l & 7;
    const int i2 = l >> 3;            // 0..127
    const int n0 = (i2 & 7) * 128;
    const int m0 = (i2 >> 3) * 128;
    if (GATHER && m0 >= cntp[bz]) return;

    const int tid = threadIdx.x;
    const int wave = tid >> 6, lane = tid & 63;
    const int waveM = wave >> 1, waveN = wave & 1;
    const int quad = lane >> 4, l16 = lane & 15;

    __shared__ __align__(16) unsigned short As[128 * 32];
    __shared__ __align__(16) unsigned short Bs[128 * 32];
    f32x4 acc[4][4] = {};

    // A staging: thread -> (row = tid>>1, 16-col half)
    const int arow = tid >> 1;
    const int col0 = (tid & 1) * 16;
    const float* rp;
    if (GATHER) {
        const int gm = m0 + arow;
        rp = (gm < cnt[bz])
                 ? X + ((size_t)bz * SEQ + idx[bz * SEQ + gm]) * DM + col0
                 : nullptr;
    } else {
        rp = X + ((size_t)bz * SEQ + m0 + arow) * DM + col0;
    }
    unsigned short* lA = As + arow * 32 + col0;

    // B (weights) async staging
    const int sr = lane >> 2, sc = (lane & 3) * 8;
    const unsigned short* gB = W + (size_t)(n0 + wave * 32 + sr) * DM + sc;
    unsigned short* lB = Bs + (wave * 32 + sr) * 32 + sc;

    const bool haveA = (!GATHER) || (rp != nullptr);
    f32x4 a0 = {}, a1 = {}, a2 = {}, a3 = {};
    if (haveA) {
        const f32x4* p4 = (const f32x4*)rp;
        a0 = p4[0]; a1 = p4[1]; a2 = p4[2]; a3 = p4[3];
    }

    for (int kt = 0; kt < DM; kt += 32) {
        stage_async(gB + kt, lB);
        stage_async(gB + kt + 16 * DM, lB + 16 * 32);
        // cast current K-tile (values prefetched last iteration -> no stall)
        ushort8 o0, o1;
        o0[0] = f2b(a0[0]); o0[1] = f2b(a0[1]); o0[2] = f2b(a0[2]); o0[3] = f2b(a0[3]);
        o0[4] = f2b(a1[0]); o0[5] = f2b(a1[1]); o0[6] = f2b(a1[2]); o0[7] = f2b(a1[3]);
        o1[0] = f2b(a2[0]); o1[1] = f2b(a2[1]); o1[2] = f2b(a2[2]); o1[3] = f2b(a2[3]);
        o1[4] = f2b(a3[0]); o1[5] = f2b(a3[1]); o1[6] = f2b(a3[2]); o1[7] = f2b(a3[3]);
        *(ushort8*)lA = o0;
        *(ushort8*)(lA + 8) = o1;
        // prefetch next K-tile; drains at the same vmcnt(0) the B stage pays
        if (haveA && kt + 32 < DM) {
            const f32x4* p4 = (const f32x4*)(rp + kt + 32);
            a0 = p4[0]; a1 = p4[1]; a2 = p4[2]; a3 = p4[3];
        }
        __syncthreads();
        frag_mfma(As, Bs, acc, waveM, waveN, quad, l16);
        __syncthreads();
    }

    if (!TROUT) {
        unsigned short* Cb = C + (size_t)bz * SEQ * DM;
#pragma unroll
        for (int i = 0; i < 4; ++i) {
            const int gmb = m0 + waveM * 64 + i * 16 + quad * 4;
#pragma unroll
            for (int j = 0; j < 4; ++j) {
                const int gn = n0 + waveN * 64 + j * 16 + l16;
                const float bv = bias[gn];
#pragma unroll
                for (int r = 0; r < 4; ++r)
                    Cb[(size_t)(gmb + r) * DM + gn] = f2b(acc[i][j][r] + bv);
            }
        }
    } else {
        unsigned short* Cb = C + (size_t)bz * (size_t)DM * SEQ;
#pragma unroll
        for (int i = 0; i < 4; ++i) {
            const int gmb = m0 + waveM * 64 + i * 16 + quad * 4;  // compacted j
#pragma unroll
            for (int j = 0; j < 4; ++j) {
                const int gn = n0 + waveN * 64 + j * 16 + l16;
                const float bv = bias[gn];
                ushort4v o;
#pragma unroll
                for (int r = 0; r < 4; ++r) o[r] = f2b(acc[i][j][r] + bv);
                *(ushort4v*)(Cb + (size_t)gn * SEQ + gmb) = o;
            }
        }
    }
}

// ---------------- scores GEMM: probs = exp(Q.Kc^T/32), + rowsum ----------------
// grid (16,16,8); swizzle batch = linear&7 (one batch per XCD: Qp_b+Kc_b in L2).
__global__ __launch_bounds__(256) void scores_gemm(
    const unsigned short* __restrict__ Qp, const unsigned short* __restrict__ Kc,
    unsigned short* __restrict__ P, float* __restrict__ rowsum,
    const int* __restrict__ cnt, const int* __restrict__ cntp, float scale) {
    const int l = blockIdx.x + 16 * (blockIdx.y + 16 * blockIdx.z);
    const int bz = l & 7;
    const int i2 = l >> 3;            // 0..255
    const int n0 = (i2 & 15) * 128;
    const int m0 = (i2 >> 4) * 128;
    if (n0 >= cntp[bz]) return;

    const int tid = threadIdx.x;
    const int wave = tid >> 6, lane = tid & 63;
    const int waveM = wave >> 1, waveN = wave & 1;
    const int quad = lane >> 4, l16 = lane & 15;

    __shared__ __align__(16) unsigned short As[128 * 32];
    __shared__ __align__(16) unsigned short Bs[128 * 32];
    f32x4 acc[4][4] = {};

    const unsigned short* Ag = Qp + (size_t)bz * SEQ * DM;
    const unsigned short* Bg = Kc + (size_t)bz * SEQ * DM;
    const int sr = lane >> 2, sc = (lane & 3) * 8;
    const unsigned short* gA = Ag + (size_t)(m0 + wave * 32 + sr) * DM + sc;
    const unsigned short* gB = Bg + (size_t)(n0 + wave * 32 + sr) * DM + sc;
    unsigned short* lA = As + (wave * 32 + sr) * 32 + sc;
    unsigned short* lB = Bs + (wave * 32 + sr) * 32 + sc;

    for (int kt = 0; kt < DM; kt += 32) {
        stage_async(gA + kt, lA);
        stage_async(gA + kt + 16 * DM, lA + 16 * 32);
        stage_async(gB + kt, lB);
        stage_async(gB + kt + 16 * DM, lB + 16 * 32);
        __syncthreads();
        frag_mfma(As, Bs, acc, waveM, waveN, quad, l16);
        __syncthreads();
    }

    unsigned short* Cb = P + (size_t)bz * SEQ * SEQ;
    const int cn = cnt[bz];
#pragma unroll
    for (int i = 0; i < 4; ++i) {
        const int gmb = m0 + waveM * 64 + i * 16 + quad * 4;
        float rpart[4] = {0.f, 0.f, 0.f, 0.f};
#pragma unroll
        for (int j = 0; j < 4; ++j) {
            const int gn = n0 + waveN * 64 + j * 16 + l16;
            const float mv = (gn < cn) ? 1.0f : 0.0f;
#pragma unroll
            for (int r = 0; r < 4; ++r) {
                const float p = mv * __expf(acc[i][j][r] * scale);
                rpart[r] += p;
                Cb[(size_t)(gmb + r) * SEQ + gn] = f2b(p);
            }
        }
#pragma unroll
        for (int r = 0; r < 4; ++r) {
            float s = rpart[r];
            s += __shfl_xor(s, 1, 64);
            s += __shfl_xor(s, 2, 64);
            s += __shfl_xor(s, 4, 64);
            s += __shfl_xor(s, 8, 64);
            if (l16 == 0)
                atomicAdd(&rowsum[bz * SEQ + gmb + r], s);
        }
    }
}

// ---------------- PV GEMM: out = (P.Vtc^T) / rowsum ----------------
// grid (8,16,8); swizzle batch = linear&7.
__global__ __launch_bounds__(256) void pv_gemm(
    const unsigned short* __restrict__ P, const unsigned short* __restrict__ Vt,
    float* __restrict__ O, const float* __restrict__ rowsum,
    const int* __restrict__ cntp) {
    const int l = blockIdx.x + 8 * (blockIdx.y + 16 * blockIdx.z);
    const int bz = l & 7;
    const int i2 = l >> 3;            // 0..127
    const int n0 = (i2 & 7) * 128;
    const int m0 = (i2 >> 3) * 128;
    const int kend = cntp[bz];

    const int tid = threadIdx.x;
    const int wave = tid >> 6, lane = tid & 63;
    const int waveM = wave >> 1, waveN = wave & 1;
    const int quad = lane >> 4, l16 = lane & 15;

    __shared__ __align__(16) unsigned short As[128 * 32];
    __shared__ __align__(16) unsigned short Bs[128 * 32];
    f32x4 acc[4][4] = {};

    const unsigned short* Ag = P + (size_t)bz * SEQ * SEQ;
    const unsigned short* Bg = Vt + (size_t)bz * (size_t)DM * SEQ;
    const int sr = lane >> 2, sc = (lane & 3) * 8;
    const unsigned short* gA = Ag + (size_t)(m0 + wave * 32 + sr) * SEQ + sc;
    const unsigned short* gB = Bg + (size_t)(n0 + wave * 32 + sr) * SEQ + sc;
    unsigned short* lA = As + (wave * 32 + sr) * 32 + sc;
    unsigned short* lB = Bs + (wave * 32 + sr) * 32 + sc;

    for (int kt = 0; kt < kend; kt += 32) {
        stage_async(gA + kt, lA);
        stage_async(gA + kt + 16 * SEQ, lA + 16 * 32);
        stage_async(gB + kt, lB);
        stage_async(gB + kt + 16 * SEQ, lB + 16 * 32);
        __syncthreads();
        frag_mfma(As, Bs, acc, waveM, waveN, quad, l16);
        __syncthreads();
    }

    float* Cb = O + (size_t)bz * SEQ * DM;
#pragma unroll
    for (int i = 0; i < 4; ++i) {
        const int gmb = m0 + waveM * 64 + i * 16 + quad * 4;
        float inv[4];
#pragma unroll
        for (int r = 0; r < 4; ++r)
            inv[r] = 1.0f / rowsum[bz * SEQ + gmb + r];
#pragma unroll
        for (int j = 0; j < 4; ++j) {
            const int gn = n0 + waveN * 64 + j * 16 + l16;
#pragma unroll
            for (int r = 0; r < 4; ++r)
                Cb[(size_t)(gmb + r) * DM + gn] = acc[i][j][r] * inv[r];
        }
    }
}

extern "C" void kernel_launch(void* const* d_in, const int* in_sizes, int n_in,
                              void* d_out, int out_size, void* d_ws, size_t ws_size,
                              hipStream_t stream) {
    const float* query = (const float*)d_in[0];
    const float* key_  = (const float*)d_in[1];
    const float* value = (const float*)d_in[2];
    const int*   mask  = (const int*)d_in[3];
    const float* Wq = (const float*)d_in[4];
    const float* bq = (const float*)d_in[5];
    const float* Wk = (const float*)d_in[6];
    const float* bk = (const float*)d_in[7];
    const float* Wv = (const float*)d_in[8];
    const float* bv = (const float*)d_in[9];
    float* out = (float*)d_out;

    char* ws = (char*)d_ws;
    const size_t MB = 1024 * 1024;
    unsigned short* Qp    = (unsigned short*)(ws);             // 32MB
    unsigned short* Kc    = (unsigned short*)(ws + 32 * MB);   // 32MB
    unsigned short* Vtc   = (unsigned short*)(ws + 64 * MB);   // 32MB
    unsigned short* probs = (unsigned short*)(ws + 96 * MB);   // 64MB
    unsigned short* wq    = (unsigned short*)(ws + 160 * MB);  // 2MB
    unsigned short* wk    = (unsigned short*)(ws + 162 * MB);  // 2MB
    unsigned short* wv    = (unsigned short*)(ws + 164 * MB);  // 2MB
    float* rowsum = (float*)(ws + 166 * MB);                   // 64KB
    int*   idx    = (int*)(ws + 166 * MB + 64 * 1024);         // 64KB
    int*   cnt    = (int*)(ws + 166 * MB + 128 * 1024);        // 32B
    int*   cntp   = (int*)(ws + 166 * MB + 128 * 1024 + 64);   // 32B

    const int NW = DM * DM;  // 1048576

    hipMemsetAsync(rowsum, 0, (size_t)BATCH * SEQ * sizeof(float), stream);
    build_idx<<<BATCH, 256, 0, stream>>>(mask, idx, cnt, cntp);

    cast_bf16<<<NW / 8 / 256, 256, 0, stream>>>(Wq, wq, NW / 8);
    cast_bf16<<<NW / 8 / 256, 256, 0, stream>>>(Wk, wk, NW / 8);
    cast_bf16<<<NW / 8 / 256, 256, 0, stream>>>(Wv, wv, NW / 8);

    const dim3 blk(256);
    const dim3 gproj(8, 16, 8);

    proj_gemm<false, false><<<gproj, blk, 0, stream>>>(
        query, wq, Qp, bq, nullptr, nullptr, nullptr);
    proj_gemm<true, false><<<gproj, blk, 0, stream>>>(
        key_, wk, Kc, bk, idx, cnt, cntp);
    proj_gemm<true, true><<<gproj, blk, 0, stream>>>(
        value, wv, Vtc, bv, idx, cnt, cntp);

    scores_gemm<<<dim3(16, 16, 8), blk, 0, stream>>>(
        Qp, Kc, probs, rowsum, cnt, cntp, 0.03125f);

    pv_gemm<<<dim3(8, 16, 8), blk, 0, stream>>>(
        probs, Vtc, out, rowsum, cntp);
}

// Round 2
// 440.605 us; speedup vs baseline: 1.1774x; 1.0828x over previous
//
#include <hip/hip_runtime.h>

// SelfAttention B=8 S=2048 D=1024 fp32 -> fp32, bf16 MFMA internally.
// R6: merge the three projection GEMMs into ONE dispatch (grid z=24,
//     p = linear>>10 selects Q/K/V). The GATHER early-exit blocks (~half of
//     K/V) previously left CUs idle for two whole dispatches; merged, the
//     block queue back-fills instantly and two launch boundaries vanish.
//     Also merges the 3 weight-cast launches into one.
// Pipeline:
//   build_idx; castW (one launch, 3 segments);
//   proj_gemm_all: Q (fused cast) -> Qp | K (gather+cast) -> Kc
//                  | V (gather+cast, transposed out) -> Vtc;
//   scores GEMM: p=(gn<cnt)?exp(s/32):0 -> bf16 probs + atomic rowsum
//   PV GEMM (K limited to cntp[b]), epilogue /rowsum -> fp32 out.
// GEMM core = m97-style: 128x128 tile, BK=32, 4 waves, 16x16x32 bf16 MFMA,
// 2-barrier K-loop; B staging async global_load_lds width=16; A fp32 loads
// software-pipelined one K-step ahead in registers, native bf16 cvt.
// Workspace (~167MB): Qp[0,32M) Kc[32,64M) Vtc[64,96M) probs[96,160M)
//   weights[160,166M) rowsum/idx/cnt/cntp after.

#define BATCH 8
#define SEQ   2048
#define DM    1024

typedef __bf16 bf16x8 __attribute__((ext_vector_type(8)));
typedef float  f32x4  __attribute__((ext_vector_type(4)));
typedef unsigned short ushort8 __attribute__((ext_vector_type(8)));
typedef unsigned short ushort4v __attribute__((ext_vector_type(4)));

__device__ __forceinline__ unsigned short f2b(float f) {
    // Native cast: compiler emits v_cvt_pk_bf16_f32 pairs (RNE).
    __bf16 h = (__bf16)f;
    return __builtin_bit_cast(unsigned short, h);
}

__device__ __forceinline__ void stage_async(const unsigned short* g,
                                            unsigned short* l) {
    __builtin_amdgcn_global_load_lds(
        (const __attribute__((address_space(1))) void*)g,
        (__attribute__((address_space(3))) void*)l, 16, 0, 0);
}

// fragment load + 4x4 MFMA for one BK=32 staged tile
__device__ __forceinline__ void frag_mfma(const unsigned short* As,
                                          const unsigned short* Bs,
                                          f32x4 acc[4][4], int waveM, int waveN,
                                          int quad, int l16) {
    bf16x8 af[4], bf[4];
#pragma unroll
    for (int i = 0; i < 4; ++i)
        af[i] = *(const bf16x8*)(As + (waveM * 64 + i * 16 + l16) * 32 + quad * 8);
#pragma unroll
    for (int j = 0; j < 4; ++j)
        bf[j] = *(const bf16x8*)(Bs + (waveN * 64 + j * 16 + l16) * 32 + quad * 8);
#pragma unroll
    for (int i = 0; i < 4; ++i)
#pragma unroll
        for (int j = 0; j < 4; ++j)
            acc[i][j] = __builtin_amdgcn_mfma_f32_16x16x32_bf16(
                af[i], bf[j], acc[i][j], 0, 0, 0);
}

// ---------------- per-batch mask compaction index ----------------
__global__ __launch_bounds__(256) void build_idx(
    const int* __restrict__ mask, int* __restrict__ idx,
    int* __restrict__ cnt, int* __restrict__ cntp) {
    const int b = blockIdx.x;
    const int* m = mask + b * SEQ;
    const int t = threadIdx.x;
    __shared__ int sums[256];
    int loc[8], s = 0;
#pragma unroll
    for (int u = 0; u < 8; ++u) { loc[u] = (m[t * 8 + u] != 0); s += loc[u]; }
    sums[t] = s;
    __syncthreads();
    for (int off = 1; off < 256; off <<= 1) {
        int v = (t >= off) ? sums[t - off] : 0;
        __syncthreads();
        sums[t] += v;
        __syncthreads();
    }
    int base = sums[t] - s;   // exclusive prefix
#pragma unroll
    for (int u = 0; u < 8; ++u)
        if (loc[u]) idx[b * SEQ + base++] = t * 8 + u;
    if (t == 255) {
        cnt[b] = sums[255];
        cntp[b] = (sums[255] + 127) & ~127;
    }
}

// ---------------- cast fp32 -> bf16 (all three weight matrices) ----------------
__global__ void cast_bf16_all(const float* __restrict__ Wq,
                              const float* __restrict__ Wk,
                              const float* __restrict__ Wv,
                              unsigned short* __restrict__ wq,
                              unsigned short* __restrict__ wk,
                              unsigned short* __restrict__ wv) {
    const int p = blockIdx.x >> 9;          // 512 blocks per matrix
    const int lb = blockIdx.x & 511;
    const float* src = (p == 0) ? Wq : (p == 1) ? Wk : Wv;
    unsigned short* dst = (p == 0) ? wq : (p == 1) ? wk : wv;
    int i = lb * blockDim.x + threadIdx.x;  // < 131072
    const f32x4* s4 = (const f32x4*)src;
    f32x4 a = s4[2 * i], b = s4[2 * i + 1];
    ushort8 o;
    o[0] = f2b(a[0]); o[1] = f2b(a[1]); o[2] = f2b(a[2]); o[3] = f2b(a[3]);
    o[4] = f2b(b[0]); o[5] = f2b(b[1]); o[6] = f2b(b[2]); o[7] = f2b(b[3]);
    ((ushort8*)dst)[i] = o;
}

// ------------- projection GEMM body with fused cast(+gather) A-staging -------------
// C[M,N] = cast(X)[M,K] * W[N,K]^T + bias.  X fp32 (gathered rows if GATHER),
// W bf16 async-staged.  TROUT: write C^T -> C[b][n][m] (V path).
// A fp32 loads software-pipelined one K-step ahead (regs); their latency
// drains under the same pre-barrier vmcnt(0) as the B stage.
template <bool GATHER, bool TROUT>
__device__ __forceinline__ void proj_body(
    const float* __restrict__ X, const unsigned short* __restrict__ W,
    unsigned short* __restrict__ C, const float* __restrict__ bias,
    const int* __restrict__ idx, const int* __restrict__ cnt,
    const int* __restrict__ cntp, int bz, int i2,
    unsigned short* As, unsigned short* Bs) {
    const int n0 = (i2 & 7) * 128;
    const int m0 = (i2 >> 3) * 128;
    if (GATHER && m0 >= cntp[bz]) return;

    const int tid = threadIdx.x;
    const int wave = tid >> 6, lane = tid & 63;
    const int waveM = wave >> 1, waveN = wave & 1;
    const int quad = lane >> 4, l16 = lane & 15;

    f32x4 acc[4][4] = {};

    // A staging: thread -> (row = tid>>1, 16-col half)
    const int arow = tid >> 1;
    const int col0 = (tid & 1) * 16;
    const float* rp;
    if (GATHER) {
        const int gm = m0 + arow;
        rp = (gm < cnt[bz])
                 ? X + ((size_t)bz * SEQ + idx[bz * SEQ + gm]) * DM + col0
                 : nullptr;
    } else {
        rp = X + ((size_t)bz * SEQ + m0 + arow) * DM + col0;
    }
    unsigned short* lA = As + arow * 32 + col0;

    // B (weights) async staging
    const int sr = lane >> 2, sc = (lane & 3) * 8;
    const unsigned short* gB = W + (size_t)(n0 + wave * 32 + sr) * DM + sc;
    unsigned short* lB = Bs + (wave * 32 + sr) * 32 + sc;

    const bool haveA = (!GATHER) || (rp != nullptr);
    f32x4 a0 = {}, a1 = {}, a2 = {}, a3 = {};
    if (haveA) {
        const f32x4* p4 = (const f32x4*)rp;
        a0 = p4[0]; a1 = p4[1]; a2 = p4[2]; a3 = p4[3];
    }

    for (int kt = 0; kt < DM; kt += 32) {
        stage_async(gB + kt, lB);
        stage_async(gB + kt + 16 * DM, lB + 16 * 32);
        // cast current K-tile (values prefetched last iteration -> no stall)
        ushort8 o0, o1;
        o0[0] = f2b(a0[0]); o0[1] = f2b(a0[1]); o0[2] = f2b(a0[2]); o0[3] = f2b(a0[3]);
        o0[4] = f2b(a1[0]); o0[5] = f2b(a1[1]); o0[6] = f2b(a1[2]); o0[7] = f2b(a1[3]);
        o1[0] = f2b(a2[0]); o1[1] = f2b(a2[1]); o1[2] = f2b(a2[2]); o1[3] = f2b(a2[3]);
        o1[4] = f2b(a3[0]); o1[5] = f2b(a3[1]); o1[6] = f2b(a3[2]); o1[7] = f2b(a3[3]);
        *(ushort8*)lA = o0;
        *(ushort8*)(lA + 8) = o1;
        // prefetch next K-tile; drains at the same vmcnt(0) the B stage pays
        if (haveA && kt + 32 < DM) {
            const f32x4* p4 = (const f32x4*)(rp + kt + 32);
            a0 = p4[0]; a1 = p4[1]; a2 = p4[2]; a3 = p4[3];
        }
        __syncthreads();
        frag_mfma(As, Bs, acc, waveM, waveN, quad, l16);
        __syncthreads();
    }

    if (!TROUT) {
        unsigned short* Cb = C + (size_t)bz * SEQ * DM;
#pragma unroll
        for (int i = 0; i < 4; ++i) {
            const int gmb = m0 + waveM * 64 + i * 16 + quad * 4;
#pragma unroll
            for (int j = 0; j < 4; ++j) {
                const int gn = n0 + waveN * 64 + j * 16 + l16;
                const float bv = bias[gn];
#pragma unroll
                for (int r = 0; r < 4; ++r)
                    Cb[(size_t)(gmb + r) * DM + gn] = f2b(acc[i][j][r] + bv);
            }
        }
    } else {
        unsigned short* Cb = C + (size_t)bz * (size_t)DM * SEQ;
#pragma unroll
        for (int i = 0; i < 4; ++i) {
            const int gmb = m0 + waveM * 64 + i * 16 + quad * 4;  // compacted j
#pragma unroll
            for (int j = 0; j < 4; ++j) {
                const int gn = n0 + waveN * 64 + j * 16 + l16;
                const float bv = bias[gn];
                ushort4v o;
#pragma unroll
                for (int r = 0; r < 4; ++r) o[r] = f2b(acc[i][j][r] + bv);
                *(ushort4v*)(Cb + (size_t)gn * SEQ + gmb) = o;
            }
        }
    }
}

// Merged Q/K/V projection dispatch.  grid (8,16,24): linear l in [0,3072);
// p = l>>10 selects projection; batch = l&7 keeps batch<->XCD affinity.
__global__ __launch_bounds__(256) void proj_gemm_all(
    const float* __restrict__ q, const float* __restrict__ k,
    const float* __restrict__ v, const unsigned short* __restrict__ wq,
    const unsigned short* __restrict__ wk, const unsigned short* __restrict__ wv,
    unsigned short* __restrict__ Qp, unsigned short* __restrict__ Kc,
    unsigned short* __restrict__ Vt, const float* __restrict__ bq,
    const float* __restrict__ bk, const float* __restrict__ bv,
    const int* __restrict__ idx, const int* __restrict__ cnt,
    const int* __restrict__ cntp) {
    const int l = blockIdx.x + 8 * (blockIdx.y + 16 * blockIdx.z);
    const int p = l >> 10;
    const int bz = l & 7;
    const int i2 = (l & 1023) >> 3;   // 0..127

    __shared__ __align__(16) unsigned short As[128 * 32];
    __shared__ __align__(16) unsigned short Bs[128 * 32];

    if (p == 0)
        proj_body<false, false>(q, wq, Qp, bq, nullptr, nullptr, nullptr, bz, i2, As, Bs);
    else if (p == 1)
        proj_body<true, false>(k, wk, Kc, bk, idx, cnt, cntp, bz, i2, As, Bs);
    else
        proj_body<true, true>(v, wv, Vt, bv, idx, cnt, cntp, bz, i2, As, Bs);
}

// ---------------- scores GEMM: probs = exp(Q.Kc^T/32), + rowsum ----------------
// grid (16,16,8); swizzle batch = linear&7 (one batch per XCD: Qp_b+Kc_b in L2).
__global__ __launch_bounds__(256) void scores_gemm(
    const unsigned short* __restrict__ Qp, const unsigned short* __restrict__ Kc,
    unsigned short* __restrict__ P, float* __restrict__ rowsum,
    const int* __restrict__ cnt, const int* __restrict__ cntp, float scale) {
    const int l = blockIdx.x + 16 * (blockIdx.y + 16 * blockIdx.z);
    const int bz = l & 7;
    const int i2 = l >> 3;            // 0..255
    const int n0 = (i2 & 15) * 128;
    const int m0 = (i2 >> 4) * 128;
    if (n0 >= cntp[bz]) return;

    const int tid = threadIdx.x;
    const int wave = tid >> 6, lane = tid & 63;
    const int waveM = wave >> 1, waveN = wave & 1;
    const int quad = lane >> 4, l16 = lane & 15;

    __shared__ __align__(16) unsigned short As[128 * 32];
    __shared__ __align__(16) unsigned short Bs[128 * 32];
    f32x4 acc[4][4] = {};

    const unsigned short* Ag = Qp + (size_t)bz * SEQ * DM;
    const unsigned short* Bg = Kc + (size_t)bz * SEQ * DM;
    const int sr = lane >> 2, sc = (lane & 3) * 8;
    const unsigned short* gA = Ag + (size_t)(m0 + wave * 32 + sr) * DM + sc;
    const unsigned short* gB = Bg + (size_t)(n0 + wave * 32 + sr) * DM + sc;
    unsigned short* lA = As + (wave * 32 + sr) * 32 + sc;
    unsigned short* lB = Bs + (wave * 32 + sr) * 32 + sc;

    for (int kt = 0; kt < DM; kt += 32) {
        stage_async(gA + kt, lA);
        stage_async(gA + kt + 16 * DM, lA + 16 * 32);
        stage_async(gB + kt, lB);
        stage_async(gB + kt + 16 * DM, lB + 16 * 32);
        __syncthreads();
        frag_mfma(As, Bs, acc, waveM, waveN, quad, l16);
        __syncthreads();
    }

    unsigned short* Cb = P + (size_t)bz * SEQ * SEQ;
    const int cn = cnt[bz];
#pragma unroll
    for (int i = 0; i < 4; ++i) {
        const int gmb = m0 + waveM * 64 + i * 16 + quad * 4;
        float rpart[4] = {0.f, 0.f, 0.f, 0.f};
#pragma unroll
        for (int j = 0; j < 4; ++j) {
            const int gn = n0 + waveN * 64 + j * 16 + l16;
            const float mv = (gn < cn) ? 1.0f : 0.0f;
#pragma unroll
            for (int r = 0; r < 4; ++r) {
                const float p = mv * __expf(acc[i][j][r] * scale);
                rpart[r] += p;
                Cb[(size_t)(gmb + r) * SEQ + gn] = f2b(p);
            }
        }
#pragma unroll
        for (int r = 0; r < 4; ++r) {
            float s = rpart[r];
            s += __shfl_xor(s, 1, 64);
            s += __shfl_xor(s, 2, 64);
            s += __shfl_xor(s, 4, 64);
            s += __shfl_xor(s, 8, 64);
            if (l16 == 0)
                atomicAdd(&rowsum[bz * SEQ + gmb + r], s);
        }
    }
}

// ---------------- PV GEMM: out = (P.Vtc^T) / rowsum ----------------
// grid (8,16,8); swizzle batch = linear&7.
__global__ __launch_bounds__(256) void pv_gemm(
    const unsigned short* __restrict__ P, const unsigned short* __restrict__ Vt,
    float* __restrict__ O, const float* __restrict__ rowsum,
    const int* __restrict__ cntp) {
    const int l = blockIdx.x + 8 * (blockIdx.y + 16 * blockIdx.z);
    const int bz = l & 7;
    const int i2 = l >> 3;            // 0..127
    const int n0 = (i2 & 7) * 128;
    const int m0 = (i2 >> 3) * 128;
    const int kend = cntp[bz];

    const int tid = threadIdx.x;
    const int wave = tid >> 6, lane = tid & 63;
    const int waveM = wave >> 1, waveN = wave & 1;
    const int quad = lane >> 4, l16 = lane & 15;

    __shared__ __align__(16) unsigned short As[128 * 32];
    __shared__ __align__(16) unsigned short Bs[128 * 32];
    f32x4 acc[4][4] = {};

    const unsigned short* Ag = P + (size_t)bz * SEQ * SEQ;
    const unsigned short* Bg = Vt + (size_t)bz * (size_t)DM * SEQ;
    const int sr = lane >> 2, sc = (lane & 3) * 8;
    const unsigned short* gA = Ag + (size_t)(m0 + wave * 32 + sr) * SEQ + sc;
    const unsigned short* gB = Bg + (size_t)(n0 + wave * 32 + sr) * SEQ + sc;
    unsigned short* lA = As + (wave * 32 + sr) * 32 + sc;
    unsigned short* lB = Bs + (wave * 32 + sr) * 32 + sc;

    for (int kt = 0; kt < kend; kt += 32) {
        stage_async(gA + kt, lA);
        stage_async(gA + kt + 16 * SEQ, lA + 16 * 32);
        stage_async(gB + kt, lB);
        stage_async(gB + kt + 16 * SEQ, lB + 16 * 32);
        __syncthreads();
        frag_mfma(As, Bs, acc, waveM, waveN, quad, l16);
        __syncthreads();
    }

    float* Cb = O + (size_t)bz * SEQ * DM;
#pragma unroll
    for (int i = 0; i < 4; ++i) {
        const int gmb = m0 + waveM * 64 + i * 16 + quad * 4;
        float inv[4];
#pragma unroll
        for (int r = 0; r < 4; ++r)
            inv[r] = 1.0f / rowsum[bz * SEQ + gmb + r];
#pragma unroll
        for (int j = 0; j < 4; ++j) {
            const int gn = n0 + waveN * 64 + j * 16 + l16;
#pragma unroll
            for (int r = 0; r < 4; ++r)
                Cb[(size_t)(gmb + r) * DM + gn] = acc[i][j][r] * inv[r];
        }
    }
}

extern "C" void kernel_launch(void* const* d_in, const int* in_sizes, int n_in,
                              void* d_out, int out_size, void* d_ws, size_t ws_size,
                              hipStream_t stream) {
    const float* query = (const float*)d_in[0];
    const float* key_  = (const float*)d_in[1];
    const float* value = (const float*)d_in[2];
    const int*   mask  = (const int*)d_in[3];
    const float* Wq = (const float*)d_in[4];
    const float* bq = (const float*)d_in[5];
    const float* Wk = (const float*)d_in[6];
    const float* bk = (const float*)d_in[7];
    const float* Wv = (const float*)d_in[8];
    const float* bv = (const float*)d_in[9];
    float* out = (float*)d_out;

    char* ws = (char*)d_ws;
    const size_t MB = 1024 * 1024;
    unsigned short* Qp    = (unsigned short*)(ws);             // 32MB
    unsigned short* Kc    = (unsigned short*)(ws + 32 * MB);   // 32MB
    unsigned short* Vtc   = (unsigned short*)(ws + 64 * MB);   // 32MB
    unsigned short* probs = (unsigned short*)(ws + 96 * MB);   // 64MB
    unsigned short* wq    = (unsigned short*)(ws + 160 * MB);  // 2MB
    unsigned short* wk    = (unsigned short*)(ws + 162 * MB);  // 2MB
    unsigned short* wv    = (unsigned short*)(ws + 164 * MB);  // 2MB
    float* rowsum = (float*)(ws + 166 * MB);                   // 64KB
    int*   idx    = (int*)(ws + 166 * MB + 64 * 1024);         // 64KB
    int*   cnt    = (int*)(ws + 166 * MB + 128 * 1024);        // 32B
    int*   cntp   = (int*)(ws + 166 * MB + 128 * 1024 + 64);   // 32B

    hipMemsetAsync(rowsum, 0, (size_t)BATCH * SEQ * sizeof(float), stream);
    build_idx<<<BATCH, 256, 0, stream>>>(mask, idx, cnt, cntp);

    cast_bf16_all<<<1536, 256, 0, stream>>>(Wq, Wk, Wv, wq, wk, wv);

    proj_gemm_all<<<dim3(8, 16, 24), dim3(256), 0, stream>>>(
        query, key_, value, wq, wk, wv, Qp, Kc, Vtc, bq, bk, bv,
        idx, cnt, cntp);

    scores_gemm<<<dim3(16, 16, 8), dim3(256), 0, stream>>>(
        Qp, Kc, probs, rowsum, cnt, cntp, 0.03125f);

    pv_gemm<<<dim3(8, 16, 8), dim3(256), 0, stream>>>(
        probs, Vtc, out, rowsum, cntp);
}